// Round 1
// baseline (687.534 us; speedup 1.0000x reference)
//
#include <hip/hip_runtime.h>
#include <math.h>

#define NO 50000
#define NR 2000
#define NE 600000
#define D  128
#define NEG_SLOPE 0.2f
#define CAP 2048   // max edges per rider cached in LDS (avg 300, max ~380)

// ---------------------------------------------------------------------------
// wsv = W @ a  (four 128-vectors), one block of 128 threads
__global__ void precompute_wv(const float* __restrict__ Ws1, const float* __restrict__ as1,
                              const float* __restrict__ Wd1, const float* __restrict__ ad1,
                              const float* __restrict__ Ws2, const float* __restrict__ as2,
                              const float* __restrict__ Wd2, const float* __restrict__ ad2,
                              float* __restrict__ wsv1, float* __restrict__ wdv1,
                              float* __restrict__ wsv2, float* __restrict__ wdv2) {
    int k = threadIdx.x;
    float s1 = 0.f, d1 = 0.f, s2 = 0.f, d2 = 0.f;
    for (int j = 0; j < D; ++j) {
        s1 += Ws1[k * D + j] * as1[j];
        d1 += Wd1[k * D + j] * ad1[j];
        s2 += Ws2[k * D + j] * as2[j];
        d2 += Wd2[k * D + j] * ad2[j];
    }
    wsv1[k] = s1; wdv1[k] = d1; wsv2[k] = s2; wdv2[k] = d2;
}

// ---------------------------------------------------------------------------
// per-order alphas: as1o = x·wsv1, as2o = relu(x)·wsv2.  One 64-lane wave/row.
__global__ void order_alphas(const float* __restrict__ x,
                             const float* __restrict__ wsv1, const float* __restrict__ wsv2,
                             float* __restrict__ as1o, float* __restrict__ as2o) {
    int wave = (blockIdx.x * blockDim.x + threadIdx.x) >> 6;
    int lane = threadIdx.x & 63;
    if (wave >= NO) return;
    const float* row = x + (size_t)wave * D;
    float x0 = row[lane], x1 = row[lane + 64];
    float a1 = x0 * wsv1[lane] + x1 * wsv1[lane + 64];
    float a2 = fmaxf(x0, 0.f) * wsv2[lane] + fmaxf(x1, 0.f) * wsv2[lane + 64];
    for (int off = 32; off; off >>= 1) {
        a1 += __shfl_down(a1, off);
        a2 += __shfl_down(a2, off);
    }
    if (lane == 0) { as1o[wave] = a1; as2o[wave] = a2; }
}

// per-rider alpha_d1 = x_rider · wdv1.  One wave per rider.
__global__ void rider_alpha(const float* __restrict__ xr, const float* __restrict__ wdv1,
                            float* __restrict__ ad1r) {
    int wave = (blockIdx.x * blockDim.x + threadIdx.x) >> 6;
    int lane = threadIdx.x & 63;
    if (wave >= NR) return;
    const float* row = xr + (size_t)wave * D;
    float a = row[lane] * wdv1[lane] + row[lane + 64] * wdv1[lane + 64];
    for (int off = 32; off; off >>= 1) a += __shfl_down(a, off);
    if (lane == 0) ad1r[wave] = a;
}

// ---------------------------------------------------------------------------
// counting sort of edges by rider
__global__ void hist_kernel(const int* __restrict__ ri, int* __restrict__ cnt) {
    int e = blockIdx.x * blockDim.x + threadIdx.x;
    if (e < NE) atomicAdd(&cnt[ri[e]], 1);
}

__global__ void scan_kernel(const int* __restrict__ cnt,
                            int* __restrict__ starts, int* __restrict__ cursor) {
    __shared__ int sums[256];
    int t = threadIdx.x;
    int v[8];
    int s = 0;
    for (int j = 0; j < 8; ++j) {
        int idx = t * 8 + j;
        int c = (idx < NR) ? cnt[idx] : 0;
        v[j] = s;
        s += c;
    }
    sums[t] = s;
    __syncthreads();
    for (int off = 1; off < 256; off <<= 1) {
        int add = (t >= off) ? sums[t - off] : 0;
        __syncthreads();
        sums[t] += add;
        __syncthreads();
    }
    int base = sums[t] - s;  // exclusive
    for (int j = 0; j < 8; ++j) {
        int idx = t * 8 + j;
        if (idx < NR) { starts[idx] = base + v[j]; cursor[idx] = base + v[j]; }
    }
}

__global__ void scatter_kernel(const int* __restrict__ oi, const int* __restrict__ ri,
                               int* __restrict__ cursor,
                               int* __restrict__ sOrd, int* __restrict__ sEid) {
    int e = blockIdx.x * blockDim.x + threadIdx.x;
    if (e < NE) {
        int r = ri[e];
        int p = atomicAdd(&cursor[r], 1);
        sOrd[p] = oi[e];
        sEid[p] = e;
    }
}

// ---------------------------------------------------------------------------
// per-rider: segment softmax over edges + weighted gather-sum of x[oi] -> t[r]
template <bool RELU_SRC>
__global__ void rider_agg(const float* __restrict__ x, const float* __restrict__ as_o,
                          const float* __restrict__ ad_r,
                          const int* __restrict__ starts, const int* __restrict__ cnt,
                          const int* __restrict__ sOrd, float* __restrict__ tout) {
    __shared__ float eL[CAP];
    __shared__ float red[256];
    int r = blockIdx.x;
    int t = threadIdx.x;
    int base = starts[r], n = cnt[r];
    float ad = ad_r[r];

    // pass 1: leaky-relu'd logits + max
    float lmax = -1e30f;
    for (int i = t; i < n; i += 256) {
        int o = sOrd[base + i];
        float e = as_o[o] + ad;
        e = (e > 0.f) ? e : NEG_SLOPE * e;
        if (i < CAP) eL[i] = e;
        lmax = fmaxf(lmax, e);
    }
    red[t] = lmax;
    __syncthreads();
    for (int off = 128; off; off >>= 1) {
        if (t < off) red[t] = fmaxf(red[t], red[t + off]);
        __syncthreads();
    }
    float m = red[0];
    __syncthreads();

    // pass 2: exp + sum
    float ls = 0.f;
    for (int i = t; i < n; i += 256) {
        float e;
        if (i < CAP) e = eL[i];
        else {
            int o = sOrd[base + i];
            e = as_o[o] + ad;
            e = (e > 0.f) ? e : NEG_SLOPE * e;
        }
        float ex = __expf(e - m);
        if (i < CAP) eL[i] = ex;
        ls += ex;
    }
    red[t] = ls;
    __syncthreads();
    for (int off = 128; off; off >>= 1) {
        if (t < off) red[t] += red[t + off];
        __syncthreads();
    }
    float inv = 1.f / (red[0] + 1e-16f);
    __syncthreads();

    // pass 3: t[r][d] = sum_i alpha_i * x[oi_i][d], d-ownership, 2 edges in flight
    int d = t & 127, half = t >> 7;
    float acc = 0.f;
    for (int i = half; i < n; i += 2) {
        float ex;
        if (i < CAP) ex = eL[i];
        else {
            int o2 = sOrd[base + i];
            float e = as_o[o2] + ad;
            e = (e > 0.f) ? e : NEG_SLOPE * e;
            ex = __expf(e - m);
        }
        float a = ex * inv;
        int o = sOrd[base + i];
        float xv = x[(size_t)o * D + d];
        if (RELU_SRC) xv = fmaxf(xv, 0.f);
        acc += a * xv;
    }
    red[t] = acc;
    __syncthreads();
    if (t < 128) tout[(size_t)r * D + t] = red[t] + red[t + 128];
}

// ---------------------------------------------------------------------------
// layer-1 epilogue: r1 = relu(t1 @ Ws1 + b1); only alpha_d2 = r1·wdv2 survives
__global__ void gemm_l1(const float* __restrict__ t1, const float* __restrict__ Ws1,
                        const float* __restrict__ b1, const float* __restrict__ wdv2,
                        float* __restrict__ ad2r) {
    __shared__ float tl[D];
    __shared__ float red[D];
    int r = blockIdx.x, d = threadIdx.x;
    tl[d] = t1[(size_t)r * D + d];
    __syncthreads();
    float acc = 0.f;
    for (int k = 0; k < D; ++k) acc += tl[k] * Ws1[k * D + d];
    float v = fmaxf(acc + b1[d], 0.f);
    red[d] = v * wdv2[d];
    __syncthreads();
    for (int off = 64; off; off >>= 1) {
        if (d < off) red[d] += red[d + off];
        __syncthreads();
    }
    if (d == 0) ad2r[r] = red[0];
}

// ---------------------------------------------------------------------------
// layer-2 epilogue fused with scoring:
//   r2[r] = t2[r] @ Ws2 + b2   (kept in LDS)
//   for each edge of r: out[eid] = sigmoid( relu(x[oi]) · r2[r] )
__global__ void gemm_l2_score(const float* __restrict__ t2, const float* __restrict__ Ws2,
                              const float* __restrict__ b2, const float* __restrict__ x,
                              const int* __restrict__ starts, const int* __restrict__ cnt,
                              const int* __restrict__ sOrd, const int* __restrict__ sEid,
                              float* __restrict__ out) {
    __shared__ float tl[D];
    __shared__ float r2L[D];
    int r = blockIdx.x, t = threadIdx.x;
    tl[t] = t2[(size_t)r * D + t];
    __syncthreads();
    float acc = 0.f;
    for (int k = 0; k < D; ++k) acc += tl[k] * Ws2[k * D + t];
    r2L[t] = acc + b2[t];
    __syncthreads();

    int base = starts[r], n = cnt[r];
    int wave = t >> 6, lane = t & 63;
    for (int i = wave; i < n; i += 2) {
        int o = sOrd[base + i];
        int eid = sEid[base + i];
        const float* row = x + (size_t)o * D;
        float p = fmaxf(row[lane], 0.f) * r2L[lane] +
                  fmaxf(row[lane + 64], 0.f) * r2L[lane + 64];
        for (int off = 32; off; off >>= 1) p += __shfl_down(p, off);
        if (lane == 0) out[eid] = 1.f / (1.f + __expf(-p));
    }
}

// ---------------------------------------------------------------------------
extern "C" void kernel_launch(void* const* d_in, const int* in_sizes, int n_in,
                              void* d_out, int out_size, void* d_ws, size_t ws_size,
                              hipStream_t stream) {
    const float* x_order = (const float*)d_in[0];
    const float* x_rider = (const float*)d_in[1];
    const int*   oi      = (const int*)d_in[2];
    const int*   ri      = (const int*)d_in[3];
    const float* Ws1 = (const float*)d_in[4];
    const float* Wd1 = (const float*)d_in[5];
    const float* as1 = (const float*)d_in[6];
    const float* ad1 = (const float*)d_in[7];
    const float* b1  = (const float*)d_in[8];
    const float* Ws2 = (const float*)d_in[9];
    const float* Wd2 = (const float*)d_in[10];
    const float* as2 = (const float*)d_in[11];
    const float* ad2 = (const float*)d_in[12];
    const float* b2  = (const float*)d_in[13];
    float* out = (float*)d_out;

    // workspace carve-up (all offsets 16B-aligned)
    char* w = (char*)d_ws;
    float* wsv1 = (float*)w; w += 512;
    float* wdv1 = (float*)w; w += 512;
    float* wsv2 = (float*)w; w += 512;
    float* wdv2 = (float*)w; w += 512;
    float* as1o = (float*)w; w += (size_t)NO * 4;      // 200000
    float* as2o = (float*)w; w += (size_t)NO * 4;
    float* ad1r = (float*)w; w += (size_t)NR * 4;      // 8000
    float* ad2r = (float*)w; w += (size_t)NR * 4;
    int* cnt    = (int*)w;   w += (size_t)NR * 4;
    int* starts = (int*)w;   w += (size_t)NR * 4;
    int* cursor = (int*)w;   w += (size_t)NR * 4;
    int* sOrd   = (int*)w;   w += (size_t)NE * 4;      // 2.4 MB
    int* sEid   = (int*)w;   w += (size_t)NE * 4;
    float* t1   = (float*)w; w += (size_t)NR * D * 4;  // 1 MB
    float* t2   = (float*)w; w += (size_t)NR * D * 4;

    hipMemsetAsync(cnt, 0, NR * sizeof(int), stream);

    precompute_wv<<<1, 128, 0, stream>>>(Ws1, as1, Wd1, ad1, Ws2, as2, Wd2, ad2,
                                         wsv1, wdv1, wsv2, wdv2);
    order_alphas<<<NO / 4, 256, 0, stream>>>(x_order, wsv1, wsv2, as1o, as2o);
    rider_alpha<<<NR / 4, 256, 0, stream>>>(x_rider, wdv1, ad1r);

    hist_kernel<<<(NE + 255) / 256, 256, 0, stream>>>(ri, cnt);
    scan_kernel<<<1, 256, 0, stream>>>(cnt, starts, cursor);
    scatter_kernel<<<(NE + 255) / 256, 256, 0, stream>>>(oi, ri, cursor, sOrd, sEid);

    rider_agg<false><<<NR, 256, 0, stream>>>(x_order, as1o, ad1r, starts, cnt, sOrd, t1);
    gemm_l1<<<NR, 128, 0, stream>>>(t1, Ws1, b1, wdv2, ad2r);
    rider_agg<true><<<NR, 256, 0, stream>>>(x_order, as2o, ad2r, starts, cnt, sOrd, t2);
    gemm_l2_score<<<NR, 128, 0, stream>>>(t2, Ws2, b2, x_order,
                                          starts, cnt, sOrd, sEid, out);
}

// Round 2
// 480.148 us; speedup vs baseline: 1.4319x; 1.4319x over previous
//
#include <hip/hip_runtime.h>
#include <math.h>

#define NO 50000
#define NR 2000
#define NE 600000
#define D  128
#define NEG_SLOPE 0.2f
#define CAP 512   // max edges per rider cached in LDS (avg 300, max ~390)

// ---------------------------------------------------------------------------
// wsv = W @ a  (four 128-vectors), one block of 128 threads
__global__ void precompute_wv(const float* __restrict__ Ws1, const float* __restrict__ as1,
                              const float* __restrict__ Wd1, const float* __restrict__ ad1,
                              const float* __restrict__ Ws2, const float* __restrict__ as2,
                              const float* __restrict__ Wd2, const float* __restrict__ ad2,
                              float* __restrict__ wsv1, float* __restrict__ wdv1,
                              float* __restrict__ wsv2, float* __restrict__ wdv2) {
    int k = threadIdx.x;
    float s1 = 0.f, d1 = 0.f, s2 = 0.f, d2 = 0.f;
    for (int j = 0; j < D; ++j) {
        s1 += Ws1[k * D + j] * as1[j];
        d1 += Wd1[k * D + j] * ad1[j];
        s2 += Ws2[k * D + j] * as2[j];
        d2 += Wd2[k * D + j] * ad2[j];
    }
    wsv1[k] = s1; wdv1[k] = d1; wsv2[k] = s2; wdv2[k] = d2;
}

// ---------------------------------------------------------------------------
// per-order alphas: as1o = x·wsv1, as2o = relu(x)·wsv2.  One 64-lane wave/row.
__global__ void order_alphas(const float* __restrict__ x,
                             const float* __restrict__ wsv1, const float* __restrict__ wsv2,
                             float* __restrict__ as1o, float* __restrict__ as2o) {
    int wave = (blockIdx.x * blockDim.x + threadIdx.x) >> 6;
    int lane = threadIdx.x & 63;
    if (wave >= NO) return;
    const float* row = x + (size_t)wave * D;
    float x0 = row[lane], x1 = row[lane + 64];
    float a1 = x0 * wsv1[lane] + x1 * wsv1[lane + 64];
    float a2 = fmaxf(x0, 0.f) * wsv2[lane] + fmaxf(x1, 0.f) * wsv2[lane + 64];
    for (int off = 32; off; off >>= 1) {
        a1 += __shfl_down(a1, off);
        a2 += __shfl_down(a2, off);
    }
    if (lane == 0) { as1o[wave] = a1; as2o[wave] = a2; }
}

// per-rider alpha_d1 = x_rider · wdv1.  One wave per rider.
__global__ void rider_alpha(const float* __restrict__ xr, const float* __restrict__ wdv1,
                            float* __restrict__ ad1r) {
    int wave = (blockIdx.x * blockDim.x + threadIdx.x) >> 6;
    int lane = threadIdx.x & 63;
    if (wave >= NR) return;
    const float* row = xr + (size_t)wave * D;
    float a = row[lane] * wdv1[lane] + row[lane + 64] * wdv1[lane + 64];
    for (int off = 32; off; off >>= 1) a += __shfl_down(a, off);
    if (lane == 0) ad1r[wave] = a;
}

// ---------------------------------------------------------------------------
// counting sort of edges by rider
__global__ void hist_kernel(const int* __restrict__ ri, int* __restrict__ cnt) {
    int e = blockIdx.x * blockDim.x + threadIdx.x;
    if (e < NE) atomicAdd(&cnt[ri[e]], 1);
}

__global__ void scan_kernel(const int* __restrict__ cnt,
                            int* __restrict__ starts, int* __restrict__ cursor) {
    __shared__ int sums[256];
    int t = threadIdx.x;
    int v[8];
    int s = 0;
    for (int j = 0; j < 8; ++j) {
        int idx = t * 8 + j;
        int c = (idx < NR) ? cnt[idx] : 0;
        v[j] = s;
        s += c;
    }
    sums[t] = s;
    __syncthreads();
    for (int off = 1; off < 256; off <<= 1) {
        int add = (t >= off) ? sums[t - off] : 0;
        __syncthreads();
        sums[t] += add;
        __syncthreads();
    }
    int base = sums[t] - s;  // exclusive
    for (int j = 0; j < 8; ++j) {
        int idx = t * 8 + j;
        if (idx < NR) { starts[idx] = base + v[j]; cursor[idx] = base + v[j]; }
    }
}

__global__ void scatter_kernel(const int* __restrict__ oi, const int* __restrict__ ri,
                               int* __restrict__ cursor,
                               int* __restrict__ sOrd) {
    int e = blockIdx.x * blockDim.x + threadIdx.x;
    if (e < NE) {
        int r = ri[e];
        int p = atomicAdd(&cursor[r], 1);
        sOrd[p] = oi[e];
    }
}

// ---------------------------------------------------------------------------
// per-rider: segment softmax over edges + weighted gather-sum of x[oi] -> t[r]
template <bool RELU_SRC>
__global__ void rider_agg(const float* __restrict__ x, const float* __restrict__ as_o,
                          const float* __restrict__ ad_r,
                          const int* __restrict__ starts, const int* __restrict__ cnt,
                          const int* __restrict__ sOrd, float* __restrict__ tout) {
    __shared__ float eL[CAP];
    __shared__ float red[256];
    int r = blockIdx.x;
    int t = threadIdx.x;
    int base = starts[r], n = cnt[r];
    float ad = ad_r[r];

    // pass 1: leaky-relu'd logits + max
    float lmax = -1e30f;
    for (int i = t; i < n; i += 256) {
        int o = sOrd[base + i];
        float e = as_o[o] + ad;
        e = (e > 0.f) ? e : NEG_SLOPE * e;
        if (i < CAP) eL[i] = e;
        lmax = fmaxf(lmax, e);
    }
    red[t] = lmax;
    __syncthreads();
    for (int off = 128; off; off >>= 1) {
        if (t < off) red[t] = fmaxf(red[t], red[t + off]);
        __syncthreads();
    }
    float m = red[0];
    __syncthreads();

    // pass 2: exp + sum (exp values cached in LDS, NOT normalized — fold 1/s at end)
    float ls = 0.f;
    for (int i = t; i < n; i += 256) {
        float e;
        if (i < CAP) e = eL[i];
        else {
            int o = sOrd[base + i];
            e = as_o[o] + ad;
            e = (e > 0.f) ? e : NEG_SLOPE * e;
        }
        float ex = __expf(e - m);
        if (i < CAP) eL[i] = ex;
        ls += ex;
    }
    red[t] = ls;
    __syncthreads();
    for (int off = 128; off; off >>= 1) {
        if (t < off) red[t] += red[t + off];
        __syncthreads();
    }
    float inv = 1.f / (red[0] + 1e-16f);
    __syncthreads();

    // pass 3: t[r][d] = inv * sum_i ex_i * x[oi_i][d]; d-ownership, 8 edges in flight
    int d = t & 127, half = t >> 7;
    float acc = 0.f;
    if (n <= CAP) {
        int i = half;
        for (; i + 6 < n; i += 8) {
            float a0 = eL[i],     a1 = eL[i + 2], a2 = eL[i + 4], a3 = eL[i + 6];
            int   o0 = sOrd[base + i],     o1 = sOrd[base + i + 2];
            int   o2 = sOrd[base + i + 4], o3 = sOrd[base + i + 6];
            float v0 = x[(size_t)o0 * D + d];
            float v1 = x[(size_t)o1 * D + d];
            float v2 = x[(size_t)o2 * D + d];
            float v3 = x[(size_t)o3 * D + d];
            if (RELU_SRC) {
                v0 = fmaxf(v0, 0.f); v1 = fmaxf(v1, 0.f);
                v2 = fmaxf(v2, 0.f); v3 = fmaxf(v3, 0.f);
            }
            acc += a0 * v0; acc += a1 * v1; acc += a2 * v2; acc += a3 * v3;
        }
        for (; i < n; i += 2) {
            int o = sOrd[base + i];
            float xv = x[(size_t)o * D + d];
            if (RELU_SRC) xv = fmaxf(xv, 0.f);
            acc += eL[i] * xv;
        }
    } else {
        for (int i = half; i < n; i += 2) {
            float ex;
            if (i < CAP) ex = eL[i];
            else {
                int o2 = sOrd[base + i];
                float e = as_o[o2] + ad;
                e = (e > 0.f) ? e : NEG_SLOPE * e;
                ex = __expf(e - m);
            }
            int o = sOrd[base + i];
            float xv = x[(size_t)o * D + d];
            if (RELU_SRC) xv = fmaxf(xv, 0.f);
            acc += ex * xv;
        }
    }
    red[t] = acc;
    __syncthreads();
    if (t < 128) tout[(size_t)r * D + t] = (red[t] + red[t + 128]) * inv;
}

// ---------------------------------------------------------------------------
// layer-1 epilogue: r1 = relu(t1 @ Ws1 + b1); only alpha_d2 = r1·wdv2 survives
__global__ void gemm_l1(const float* __restrict__ t1, const float* __restrict__ Ws1,
                        const float* __restrict__ b1, const float* __restrict__ wdv2,
                        float* __restrict__ ad2r) {
    __shared__ float tl[D];
    __shared__ float red[D];
    int r = blockIdx.x, d = threadIdx.x;
    tl[d] = t1[(size_t)r * D + d];
    __syncthreads();
    float acc = 0.f;
    for (int k = 0; k < D; ++k) acc += tl[k] * Ws1[k * D + d];
    float v = fmaxf(acc + b1[d], 0.f);
    red[d] = v * wdv2[d];
    __syncthreads();
    for (int off = 64; off; off >>= 1) {
        if (d < off) red[d] += red[d + off];
        __syncthreads();
    }
    if (d == 0) ad2r[r] = red[0];
}

// layer-2 epilogue: r2 = t2 @ Ws2 + b2, materialized to workspace
__global__ void gemm_l2(const float* __restrict__ t2, const float* __restrict__ Ws2,
                        const float* __restrict__ b2, float* __restrict__ r2) {
    __shared__ float tl[D];
    int r = blockIdx.x, d = threadIdx.x;
    tl[d] = t2[(size_t)r * D + d];
    __syncthreads();
    float acc = 0.f;
    for (int k = 0; k < D; ++k) acc += tl[k] * Ws2[k * D + d];
    r2[(size_t)r * D + d] = acc + b2[d];
}

// ---------------------------------------------------------------------------
// edge-parallel scoring: one 64-lane wave per edge
__global__ void score_edges(const float* __restrict__ x, const float* __restrict__ r2,
                            const int* __restrict__ oi, const int* __restrict__ ri,
                            float* __restrict__ out) {
    int gid = blockIdx.x * blockDim.x + threadIdx.x;
    int e = gid >> 6, lane = gid & 63;
    if (e >= NE) return;
    int o = oi[e], r = ri[e];
    const float2* xr = (const float2*)x + (size_t)o * 64;
    const float2* rr = (const float2*)r2 + (size_t)r * 64;
    float2 xv = xr[lane], rv = rr[lane];
    float p = fmaxf(xv.x, 0.f) * rv.x + fmaxf(xv.y, 0.f) * rv.y;
    for (int off = 32; off; off >>= 1) p += __shfl_down(p, off);
    if (lane == 0) out[e] = 1.f / (1.f + __expf(-p));
}

// ---------------------------------------------------------------------------
extern "C" void kernel_launch(void* const* d_in, const int* in_sizes, int n_in,
                              void* d_out, int out_size, void* d_ws, size_t ws_size,
                              hipStream_t stream) {
    const float* x_order = (const float*)d_in[0];
    const float* x_rider = (const float*)d_in[1];
    const int*   oi      = (const int*)d_in[2];
    const int*   ri      = (const int*)d_in[3];
    const float* Ws1 = (const float*)d_in[4];
    const float* Wd1 = (const float*)d_in[5];
    const float* as1 = (const float*)d_in[6];
    const float* ad1 = (const float*)d_in[7];
    const float* b1  = (const float*)d_in[8];
    const float* Ws2 = (const float*)d_in[9];
    const float* Wd2 = (const float*)d_in[10];
    const float* as2 = (const float*)d_in[11];
    const float* ad2 = (const float*)d_in[12];
    const float* b2  = (const float*)d_in[13];
    float* out = (float*)d_out;

    // workspace carve-up (all offsets 16B-aligned)
    char* w = (char*)d_ws;
    float* wsv1 = (float*)w; w += 512;
    float* wdv1 = (float*)w; w += 512;
    float* wsv2 = (float*)w; w += 512;
    float* wdv2 = (float*)w; w += 512;
    float* as1o = (float*)w; w += (size_t)NO * 4;      // 200000
    float* as2o = (float*)w; w += (size_t)NO * 4;
    float* ad1r = (float*)w; w += (size_t)NR * 4;      // 8000
    float* ad2r = (float*)w; w += (size_t)NR * 4;
    int* cnt    = (int*)w;   w += (size_t)NR * 4;
    int* starts = (int*)w;   w += (size_t)NR * 4;
    int* cursor = (int*)w;   w += (size_t)NR * 4;
    int* sOrd   = (int*)w;   w += (size_t)NE * 4;      // 2.4 MB
    float* t1   = (float*)w; w += (size_t)NR * D * 4;  // 1 MB
    float* t2   = (float*)w; w += (size_t)NR * D * 4;
    float* r2   = (float*)w; w += (size_t)NR * D * 4;

    hipMemsetAsync(cnt, 0, NR * sizeof(int), stream);

    precompute_wv<<<1, 128, 0, stream>>>(Ws1, as1, Wd1, ad1, Ws2, as2, Wd2, ad2,
                                         wsv1, wdv1, wsv2, wdv2);
    order_alphas<<<NO / 4, 256, 0, stream>>>(x_order, wsv1, wsv2, as1o, as2o);
    rider_alpha<<<NR / 4, 256, 0, stream>>>(x_rider, wdv1, ad1r);

    hist_kernel<<<(NE + 255) / 256, 256, 0, stream>>>(ri, cnt);
    scan_kernel<<<1, 256, 0, stream>>>(cnt, starts, cursor);
    scatter_kernel<<<(NE + 255) / 256, 256, 0, stream>>>(oi, ri, cursor, sOrd);

    rider_agg<false><<<NR, 256, 0, stream>>>(x_order, as1o, ad1r, starts, cnt, sOrd, t1);
    gemm_l1<<<NR, 128, 0, stream>>>(t1, Ws1, b1, wdv2, ad2r);
    rider_agg<true><<<NR, 256, 0, stream>>>(x_order, as2o, ad2r, starts, cnt, sOrd, t2);
    gemm_l2<<<NR, 128, 0, stream>>>(t2, Ws2, b2, r2);
    score_edges<<<(NE + 3) / 4, 256, 0, stream>>>(x_order, r2, oi, ri, out);
}

// Round 3
// 424.844 us; speedup vs baseline: 1.6183x; 1.1302x over previous
//
#include <hip/hip_runtime.h>
#include <math.h>

#define NO 50000
#define NR 2000
#define NE 600000
#define D  128
#define NEG_SLOPE 0.2f
#define CAP 512   // max edges per rider cached in LDS (avg 300, max ~390)

// ---------------------------------------------------------------------------
// wsv = W @ a  (four 128-vectors), one block of 128 threads
__global__ void precompute_wv(const float* __restrict__ Ws1, const float* __restrict__ as1,
                              const float* __restrict__ Wd1, const float* __restrict__ ad1,
                              const float* __restrict__ Ws2, const float* __restrict__ as2,
                              const float* __restrict__ Wd2, const float* __restrict__ ad2,
                              float* __restrict__ wsv1, float* __restrict__ wdv1,
                              float* __restrict__ wsv2, float* __restrict__ wdv2) {
    int k = threadIdx.x;
    float s1 = 0.f, d1 = 0.f, s2 = 0.f, d2 = 0.f;
    for (int j = 0; j < D; ++j) {
        s1 += Ws1[k * D + j] * as1[j];
        d1 += Wd1[k * D + j] * ad1[j];
        s2 += Ws2[k * D + j] * as2[j];
        d2 += Wd2[k * D + j] * ad2[j];
    }
    wsv1[k] = s1; wdv1[k] = d1; wsv2[k] = s2; wdv2[k] = d2;
}

// ---------------------------------------------------------------------------
// per-order alphas: as1o = x·wsv1, as2o = relu(x)·wsv2.  One 64-lane wave/row.
__global__ void order_alphas(const float* __restrict__ x,
                             const float* __restrict__ wsv1, const float* __restrict__ wsv2,
                             float* __restrict__ as1o, float* __restrict__ as2o) {
    int wave = (blockIdx.x * blockDim.x + threadIdx.x) >> 6;
    int lane = threadIdx.x & 63;
    if (wave >= NO) return;
    const float* row = x + (size_t)wave * D;
    float x0 = row[lane], x1 = row[lane + 64];
    float a1 = x0 * wsv1[lane] + x1 * wsv1[lane + 64];
    float a2 = fmaxf(x0, 0.f) * wsv2[lane] + fmaxf(x1, 0.f) * wsv2[lane + 64];
    for (int off = 32; off; off >>= 1) {
        a1 += __shfl_down(a1, off);
        a2 += __shfl_down(a2, off);
    }
    if (lane == 0) { as1o[wave] = a1; as2o[wave] = a2; }
}

// per-rider alpha_d1 = x_rider · wdv1.  One wave per rider.
__global__ void rider_alpha(const float* __restrict__ xr, const float* __restrict__ wdv1,
                            float* __restrict__ ad1r) {
    int wave = (blockIdx.x * blockDim.x + threadIdx.x) >> 6;
    int lane = threadIdx.x & 63;
    if (wave >= NR) return;
    const float* row = xr + (size_t)wave * D;
    float a = row[lane] * wdv1[lane] + row[lane + 64] * wdv1[lane + 64];
    for (int off = 32; off; off >>= 1) a += __shfl_down(a, off);
    if (lane == 0) ad1r[wave] = a;
}

// ---------------------------------------------------------------------------
// counting sort of edges by rider
__global__ void hist_kernel(const int* __restrict__ ri, int* __restrict__ cnt) {
    int e = blockIdx.x * blockDim.x + threadIdx.x;
    if (e < NE) atomicAdd(&cnt[ri[e]], 1);
}

__global__ void scan_kernel(const int* __restrict__ cnt,
                            int* __restrict__ starts, int* __restrict__ cursor) {
    __shared__ int sums[256];
    int t = threadIdx.x;
    int v[8];
    int s = 0;
    for (int j = 0; j < 8; ++j) {
        int idx = t * 8 + j;
        int c = (idx < NR) ? cnt[idx] : 0;
        v[j] = s;
        s += c;
    }
    sums[t] = s;
    __syncthreads();
    for (int off = 1; off < 256; off <<= 1) {
        int add = (t >= off) ? sums[t - off] : 0;
        __syncthreads();
        sums[t] += add;
        __syncthreads();
    }
    int base = sums[t] - s;  // exclusive
    for (int j = 0; j < 8; ++j) {
        int idx = t * 8 + j;
        if (idx < NR) { starts[idx] = base + v[j]; cursor[idx] = base + v[j]; }
    }
}

__global__ void scatter_kernel(const int* __restrict__ oi, const int* __restrict__ ri,
                               int* __restrict__ cursor,
                               int* __restrict__ sOrd) {
    int e = blockIdx.x * blockDim.x + threadIdx.x;
    if (e < NE) {
        int r = ri[e];
        int p = atomicAdd(&cursor[r], 1);
        sOrd[p] = oi[e];
    }
}

// ---------------------------------------------------------------------------
// per-rider: segment softmax over edges + weighted gather-sum of x[oi] -> t[r]
// Pass 3 layout: 8 groups x 32 lanes; lane lq owns d = lq*4..lq*4+3 (float4).
template <bool RELU_SRC>
__global__ void rider_agg(const float* __restrict__ x, const float* __restrict__ as_o,
                          const float* __restrict__ ad_r,
                          const int* __restrict__ starts, const int* __restrict__ cnt,
                          const int* __restrict__ sOrd, float* __restrict__ tout) {
    __shared__ float eL[CAP];
    __shared__ int   sO[CAP];
    __shared__ float red[256];
    __shared__ float4 red4[256];
    int r = blockIdx.x;
    int t = threadIdx.x;
    int base = starts[r], n = cnt[r];
    float ad = ad_r[r];

    // pass 1: leaky-relu'd logits + max (cache logits + order idx in LDS)
    float lmax = -1e30f;
    for (int i = t; i < n; i += 256) {
        int o = sOrd[base + i];
        float e = as_o[o] + ad;
        e = (e > 0.f) ? e : NEG_SLOPE * e;
        if (i < CAP) { eL[i] = e; sO[i] = o; }
        lmax = fmaxf(lmax, e);
    }
    red[t] = lmax;
    __syncthreads();
    for (int off = 128; off; off >>= 1) {
        if (t < off) red[t] = fmaxf(red[t], red[t + off]);
        __syncthreads();
    }
    float m = red[0];
    __syncthreads();

    // pass 2: exp + sum (exp values cached, 1/s folded into the final write)
    float ls = 0.f;
    for (int i = t; i < n; i += 256) {
        float e;
        if (i < CAP) e = eL[i];
        else {
            int o = sOrd[base + i];
            e = as_o[o] + ad;
            e = (e > 0.f) ? e : NEG_SLOPE * e;
        }
        float ex = __expf(e - m);
        if (i < CAP) eL[i] = ex;
        ls += ex;
    }
    red[t] = ls;
    __syncthreads();
    for (int off = 128; off; off >>= 1) {
        if (t < off) red[t] += red[t + off];
        __syncthreads();
    }
    float inv = 1.f / (red[0] + 1e-16f);
    __syncthreads();

    // pass 3: float4 gather, 8 edge-groups, 2 loads in flight per thread
    int grp = t >> 5;      // 0..7
    int lq  = t & 31;      // float4 slot: d = lq*4..lq*4+3
    float4 acc = make_float4(0.f, 0.f, 0.f, 0.f);
    if (n <= CAP) {
        int i = grp;
        for (; i + 8 < n; i += 16) {
            float a0 = eL[i], a1 = eL[i + 8];
            int   o0 = sO[i], o1 = sO[i + 8];
            float4 v0 = ((const float4*)(x + (size_t)o0 * D))[lq];
            float4 v1 = ((const float4*)(x + (size_t)o1 * D))[lq];
            if (RELU_SRC) {
                v0.x = fmaxf(v0.x, 0.f); v0.y = fmaxf(v0.y, 0.f);
                v0.z = fmaxf(v0.z, 0.f); v0.w = fmaxf(v0.w, 0.f);
                v1.x = fmaxf(v1.x, 0.f); v1.y = fmaxf(v1.y, 0.f);
                v1.z = fmaxf(v1.z, 0.f); v1.w = fmaxf(v1.w, 0.f);
            }
            acc.x += a0 * v0.x + a1 * v1.x;
            acc.y += a0 * v0.y + a1 * v1.y;
            acc.z += a0 * v0.z + a1 * v1.z;
            acc.w += a0 * v0.w + a1 * v1.w;
        }
        if (i < n) {
            float a = eL[i];
            int   o = sO[i];
            float4 v = ((const float4*)(x + (size_t)o * D))[lq];
            if (RELU_SRC) {
                v.x = fmaxf(v.x, 0.f); v.y = fmaxf(v.y, 0.f);
                v.z = fmaxf(v.z, 0.f); v.w = fmaxf(v.w, 0.f);
            }
            acc.x += a * v.x; acc.y += a * v.y;
            acc.z += a * v.z; acc.w += a * v.w;
        }
    } else {
        for (int i = grp; i < n; i += 8) {
            float a;
            int o;
            if (i < CAP) { a = eL[i]; o = sO[i]; }
            else {
                o = sOrd[base + i];
                float e = as_o[o] + ad;
                e = (e > 0.f) ? e : NEG_SLOPE * e;
                a = __expf(e - m);
            }
            float4 v = ((const float4*)(x + (size_t)o * D))[lq];
            if (RELU_SRC) {
                v.x = fmaxf(v.x, 0.f); v.y = fmaxf(v.y, 0.f);
                v.z = fmaxf(v.z, 0.f); v.w = fmaxf(v.w, 0.f);
            }
            acc.x += a * v.x; acc.y += a * v.y;
            acc.z += a * v.z; acc.w += a * v.w;
        }
    }
    red4[t] = acc;
    __syncthreads();
    if (t < 32) {
        float4 s = red4[t];
        for (int g = 1; g < 8; ++g) {
            float4 v = red4[g * 32 + t];
            s.x += v.x; s.y += v.y; s.z += v.z; s.w += v.w;
        }
        s.x *= inv; s.y *= inv; s.z *= inv; s.w *= inv;
        ((float4*)(tout + (size_t)r * D))[t] = s;
    }
}

// ---------------------------------------------------------------------------
// layer-1 epilogue: r1 = relu(t1 @ Ws1 + b1); only alpha_d2 = r1·wdv2 survives
__global__ void gemm_l1(const float* __restrict__ t1, const float* __restrict__ Ws1,
                        const float* __restrict__ b1, const float* __restrict__ wdv2,
                        float* __restrict__ ad2r) {
    __shared__ float tl[D];
    __shared__ float red[D];
    int r = blockIdx.x, d = threadIdx.x;
    tl[d] = t1[(size_t)r * D + d];
    __syncthreads();
    float acc = 0.f;
    for (int k = 0; k < D; ++k) acc += tl[k] * Ws1[k * D + d];
    float v = fmaxf(acc + b1[d], 0.f);
    red[d] = v * wdv2[d];
    __syncthreads();
    for (int off = 64; off; off >>= 1) {
        if (d < off) red[d] += red[d + off];
        __syncthreads();
    }
    if (d == 0) ad2r[r] = red[0];
}

// layer-2 epilogue: r2 = t2 @ Ws2 + b2, materialized to workspace
__global__ void gemm_l2(const float* __restrict__ t2, const float* __restrict__ Ws2,
                        const float* __restrict__ b2, float* __restrict__ r2) {
    __shared__ float tl[D];
    int r = blockIdx.x, d = threadIdx.x;
    tl[d] = t2[(size_t)r * D + d];
    __syncthreads();
    float acc = 0.f;
    for (int k = 0; k < D; ++k) acc += tl[k] * Ws2[k * D + d];
    r2[(size_t)r * D + d] = acc + b2[d];
}

// ---------------------------------------------------------------------------
// edge-parallel scoring: one 32-lane half-wave per edge, float4 loads
__global__ void score_edges(const float* __restrict__ x, const float* __restrict__ r2,
                            const int* __restrict__ oi, const int* __restrict__ ri,
                            float* __restrict__ out) {
    int gid = blockIdx.x * blockDim.x + threadIdx.x;
    int e  = gid >> 5;
    int lq = gid & 31;
    if (e >= NE) return;
    int o = oi[e], r = ri[e];
    float4 xv = ((const float4*)(x  + (size_t)o * D))[lq];
    float4 rv = ((const float4*)(r2 + (size_t)r * D))[lq];
    float p = fmaxf(xv.x, 0.f) * rv.x + fmaxf(xv.y, 0.f) * rv.y +
              fmaxf(xv.z, 0.f) * rv.z + fmaxf(xv.w, 0.f) * rv.w;
    p += __shfl_xor(p, 16);
    p += __shfl_xor(p, 8);
    p += __shfl_xor(p, 4);
    p += __shfl_xor(p, 2);
    p += __shfl_xor(p, 1);
    if (lq == 0) out[e] = 1.f / (1.f + __expf(-p));
}

// ---------------------------------------------------------------------------
extern "C" void kernel_launch(void* const* d_in, const int* in_sizes, int n_in,
                              void* d_out, int out_size, void* d_ws, size_t ws_size,
                              hipStream_t stream) {
    const float* x_order = (const float*)d_in[0];
    const float* x_rider = (const float*)d_in[1];
    const int*   oi      = (const int*)d_in[2];
    const int*   ri      = (const int*)d_in[3];
    const float* Ws1 = (const float*)d_in[4];
    const float* Wd1 = (const float*)d_in[5];
    const float* as1 = (const float*)d_in[6];
    const float* ad1 = (const float*)d_in[7];
    const float* b1  = (const float*)d_in[8];
    const float* Ws2 = (const float*)d_in[9];
    const float* Wd2 = (const float*)d_in[10];
    const float* as2 = (const float*)d_in[11];
    const float* ad2 = (const float*)d_in[12];
    const float* b2  = (const float*)d_in[13];
    float* out = (float*)d_out;

    // workspace carve-up (all offsets 16B-aligned)
    char* w = (char*)d_ws;
    float* wsv1 = (float*)w; w += 512;
    float* wdv1 = (float*)w; w += 512;
    float* wsv2 = (float*)w; w += 512;
    float* wdv2 = (float*)w; w += 512;
    float* as1o = (float*)w; w += (size_t)NO * 4;      // 200000
    float* as2o = (float*)w; w += (size_t)NO * 4;
    float* ad1r = (float*)w; w += (size_t)NR * 4;      // 8000
    float* ad2r = (float*)w; w += (size_t)NR * 4;
    int* cnt    = (int*)w;   w += (size_t)NR * 4;
    int* starts = (int*)w;   w += (size_t)NR * 4;
    int* cursor = (int*)w;   w += (size_t)NR * 4;
    int* sOrd   = (int*)w;   w += (size_t)NE * 4;      // 2.4 MB
    float* t1   = (float*)w; w += (size_t)NR * D * 4;  // 1 MB
    float* t2   = (float*)w; w += (size_t)NR * D * 4;
    float* r2   = (float*)w; w += (size_t)NR * D * 4;

    hipMemsetAsync(cnt, 0, NR * sizeof(int), stream);

    precompute_wv<<<1, 128, 0, stream>>>(Ws1, as1, Wd1, ad1, Ws2, as2, Wd2, ad2,
                                         wsv1, wdv1, wsv2, wdv2);
    order_alphas<<<NO / 4, 256, 0, stream>>>(x_order, wsv1, wsv2, as1o, as2o);
    rider_alpha<<<NR / 4, 256, 0, stream>>>(x_rider, wdv1, ad1r);

    hist_kernel<<<(NE + 255) / 256, 256, 0, stream>>>(ri, cnt);
    scan_kernel<<<1, 256, 0, stream>>>(cnt, starts, cursor);
    scatter_kernel<<<(NE + 255) / 256, 256, 0, stream>>>(oi, ri, cursor, sOrd);

    rider_agg<false><<<NR, 256, 0, stream>>>(x_order, as1o, ad1r, starts, cnt, sOrd, t1);
    gemm_l1<<<NR, 128, 0, stream>>>(t1, Ws1, b1, wdv2, ad2r);
    rider_agg<true><<<NR, 256, 0, stream>>>(x_order, as2o, ad2r, starts, cnt, sOrd, t2);
    gemm_l2<<<NR, 128, 0, stream>>>(t2, Ws2, b2, r2);
    score_edges<<<NE / 8, 256, 0, stream>>>(x_order, r2, oi, ri, out);
}

// Round 4
// 317.236 us; speedup vs baseline: 2.1673x; 1.3392x over previous
//
#include <hip/hip_runtime.h>
#include <math.h>

#define NO 50000
#define NR 2000
#define NE 600000
#define D  128
#define NEG_SLOPE 0.2f
#define CAP 512   // max edges per rider cached in LDS (avg 300, max ~390)
#define NB 256    // sort chunk blocks
#define CH ((NE + NB - 1) / NB)   // 2344 edges per chunk

// ---------------------------------------------------------------------------
// wsv = W @ a  (four 128-vectors), one block of 128 threads
__global__ void precompute_wv(const float* __restrict__ Ws1, const float* __restrict__ as1,
                              const float* __restrict__ Wd1, const float* __restrict__ ad1,
                              const float* __restrict__ Ws2, const float* __restrict__ as2,
                              const float* __restrict__ Wd2, const float* __restrict__ ad2,
                              float* __restrict__ wsv1, float* __restrict__ wdv1,
                              float* __restrict__ wsv2, float* __restrict__ wdv2) {
    int k = threadIdx.x;
    float s1 = 0.f, d1 = 0.f, s2 = 0.f, d2 = 0.f;
    for (int j = 0; j < D; ++j) {
        s1 += Ws1[k * D + j] * as1[j];
        d1 += Wd1[k * D + j] * ad1[j];
        s2 += Ws2[k * D + j] * as2[j];
        d2 += Wd2[k * D + j] * ad2[j];
    }
    wsv1[k] = s1; wdv1[k] = d1; wsv2[k] = s2; wdv2[k] = d2;
}

// ---------------------------------------------------------------------------
// per-order alphas: as1o = x·wsv1, as2o = relu(x)·wsv2.  One 64-lane wave/row.
__global__ void order_alphas(const float* __restrict__ x,
                             const float* __restrict__ wsv1, const float* __restrict__ wsv2,
                             float* __restrict__ as1o, float* __restrict__ as2o) {
    int wave = (blockIdx.x * blockDim.x + threadIdx.x) >> 6;
    int lane = threadIdx.x & 63;
    if (wave >= NO) return;
    const float* row = x + (size_t)wave * D;
    float x0 = row[lane], x1 = row[lane + 64];
    float a1 = x0 * wsv1[lane] + x1 * wsv1[lane + 64];
    float a2 = fmaxf(x0, 0.f) * wsv2[lane] + fmaxf(x1, 0.f) * wsv2[lane + 64];
    for (int off = 32; off; off >>= 1) {
        a1 += __shfl_down(a1, off);
        a2 += __shfl_down(a2, off);
    }
    if (lane == 0) { as1o[wave] = a1; as2o[wave] = a2; }
}

// per-rider alpha_d1 = x_rider · wdv1.  One wave per rider.
__global__ void rider_alpha(const float* __restrict__ xr, const float* __restrict__ wdv1,
                            float* __restrict__ ad1r) {
    int wave = (blockIdx.x * blockDim.x + threadIdx.x) >> 6;
    int lane = threadIdx.x & 63;
    if (wave >= NR) return;
    const float* row = xr + (size_t)wave * D;
    float a = row[lane] * wdv1[lane] + row[lane + 64] * wdv1[lane + 64];
    for (int off = 32; off; off >>= 1) a += __shfl_down(a, off);
    if (lane == 0) ad1r[wave] = a;
}

// ---------------------------------------------------------------------------
// contention-free counting sort of edges by rider (block-histogram method)

// Phase A: per-chunk LDS histogram -> blockHist[r * NB + b]
__global__ void blockhist_kernel(const int* __restrict__ ri, int* __restrict__ blockHist) {
    __shared__ int h[NR];
    int b = blockIdx.x, t = threadIdx.x;
    for (int i = t; i < NR; i += 256) h[i] = 0;
    __syncthreads();
    int lo = b * CH;
    int hi = lo + CH; if (hi > NE) hi = NE;
    for (int i = lo + t; i < hi; i += 256) atomicAdd(&h[ri[i]], 1);
    __syncthreads();
    for (int i = t; i < NR; i += 256) blockHist[(size_t)i * NB + b] = h[i];
}

// Phase B1: per-rider exclusive scan across chunks (in place) + rider totals
__global__ void rowscan_kernel(int* __restrict__ blockHist, int* __restrict__ total) {
    int r = blockIdx.x * blockDim.x + threadIdx.x;
    if (r >= NR) return;
    int* row = blockHist + (size_t)r * NB;
    int run = 0;
    for (int b = 0; b < NB; ++b) { int v = row[b]; row[b] = run; run += v; }
    total[r] = run;
}

// Phase B2: exclusive scan over rider totals -> starts
__global__ void scan_kernel(const int* __restrict__ total, int* __restrict__ starts) {
    __shared__ int sums[256];
    int t = threadIdx.x;
    int v[8];
    int s = 0;
    for (int j = 0; j < 8; ++j) {
        int idx = t * 8 + j;
        int c = (idx < NR) ? total[idx] : 0;
        v[j] = s;
        s += c;
    }
    sums[t] = s;
    __syncthreads();
    for (int off = 1; off < 256; off <<= 1) {
        int add = (t >= off) ? sums[t - off] : 0;
        __syncthreads();
        sums[t] += add;
        __syncthreads();
    }
    int base = sums[t] - s;  // exclusive
    for (int j = 0; j < 8; ++j) {
        int idx = t * 8 + j;
        if (idx < NR) starts[idx] = base + v[j];
    }
}

// Phase C: scatter using starts + per-chunk offsets + LDS-local ranks
__global__ void scatter_kernel(const int* __restrict__ oi, const int* __restrict__ ri,
                               const int* __restrict__ starts,
                               const int* __restrict__ blockHist,
                               int* __restrict__ sOrd) {
    __shared__ int h[NR];
    int b = blockIdx.x, t = threadIdx.x;
    for (int i = t; i < NR; i += 256) h[i] = 0;
    __syncthreads();
    int lo = b * CH;
    int hi = lo + CH; if (hi > NE) hi = NE;
    for (int i = lo + t; i < hi; i += 256) {
        int r = ri[i];
        int rank = atomicAdd(&h[r], 1);
        int pos = starts[r] + blockHist[(size_t)r * NB + b] + rank;
        sOrd[pos] = oi[i];
    }
}

// ---------------------------------------------------------------------------
// per-rider: segment softmax over edges + weighted gather-sum of x[oi] -> t[r]
// Pass 3 layout: 8 groups x 32 lanes; lane lq owns d = lq*4..lq*4+3 (float4).
template <bool RELU_SRC>
__global__ void rider_agg(const float* __restrict__ x, const float* __restrict__ as_o,
                          const float* __restrict__ ad_r,
                          const int* __restrict__ starts, const int* __restrict__ cnt,
                          const int* __restrict__ sOrd, float* __restrict__ tout) {
    __shared__ float eL[CAP];
    __shared__ int   sO[CAP];
    __shared__ float red[256];
    __shared__ float4 red4[256];
    int r = blockIdx.x;
    int t = threadIdx.x;
    int base = starts[r], n = cnt[r];
    float ad = ad_r[r];

    // pass 1: leaky-relu'd logits + max (cache logits + order idx in LDS)
    float lmax = -1e30f;
    for (int i = t; i < n; i += 256) {
        int o = sOrd[base + i];
        float e = as_o[o] + ad;
        e = (e > 0.f) ? e : NEG_SLOPE * e;
        if (i < CAP) { eL[i] = e; sO[i] = o; }
        lmax = fmaxf(lmax, e);
    }
    red[t] = lmax;
    __syncthreads();
    for (int off = 128; off; off >>= 1) {
        if (t < off) red[t] = fmaxf(red[t], red[t + off]);
        __syncthreads();
    }
    float m = red[0];
    __syncthreads();

    // pass 2: exp + sum (exp values cached, 1/s folded into the final write)
    float ls = 0.f;
    for (int i = t; i < n; i += 256) {
        float e;
        if (i < CAP) e = eL[i];
        else {
            int o = sOrd[base + i];
            e = as_o[o] + ad;
            e = (e > 0.f) ? e : NEG_SLOPE * e;
        }
        float ex = __expf(e - m);
        if (i < CAP) eL[i] = ex;
        ls += ex;
    }
    red[t] = ls;
    __syncthreads();
    for (int off = 128; off; off >>= 1) {
        if (t < off) red[t] += red[t + off];
        __syncthreads();
    }
    float inv = 1.f / (red[0] + 1e-16f);
    __syncthreads();

    // pass 3: float4 gather, 8 edge-groups, 2 loads in flight per thread
    int grp = t >> 5;      // 0..7
    int lq  = t & 31;      // float4 slot: d = lq*4..lq*4+3
    float4 acc = make_float4(0.f, 0.f, 0.f, 0.f);
    if (n <= CAP) {
        int i = grp;
        for (; i + 8 < n; i += 16) {
            float a0 = eL[i], a1 = eL[i + 8];
            int   o0 = sO[i], o1 = sO[i + 8];
            float4 v0 = ((const float4*)(x + (size_t)o0 * D))[lq];
            float4 v1 = ((const float4*)(x + (size_t)o1 * D))[lq];
            if (RELU_SRC) {
                v0.x = fmaxf(v0.x, 0.f); v0.y = fmaxf(v0.y, 0.f);
                v0.z = fmaxf(v0.z, 0.f); v0.w = fmaxf(v0.w, 0.f);
                v1.x = fmaxf(v1.x, 0.f); v1.y = fmaxf(v1.y, 0.f);
                v1.z = fmaxf(v1.z, 0.f); v1.w = fmaxf(v1.w, 0.f);
            }
            acc.x += a0 * v0.x + a1 * v1.x;
            acc.y += a0 * v0.y + a1 * v1.y;
            acc.z += a0 * v0.z + a1 * v1.z;
            acc.w += a0 * v0.w + a1 * v1.w;
        }
        if (i < n) {
            float a = eL[i];
            int   o = sO[i];
            float4 v = ((const float4*)(x + (size_t)o * D))[lq];
            if (RELU_SRC) {
                v.x = fmaxf(v.x, 0.f); v.y = fmaxf(v.y, 0.f);
                v.z = fmaxf(v.z, 0.f); v.w = fmaxf(v.w, 0.f);
            }
            acc.x += a * v.x; acc.y += a * v.y;
            acc.z += a * v.z; acc.w += a * v.w;
        }
    } else {
        for (int i = grp; i < n; i += 8) {
            float a;
            int o;
            if (i < CAP) { a = eL[i]; o = sO[i]; }
            else {
                o = sOrd[base + i];
                float e = as_o[o] + ad;
                e = (e > 0.f) ? e : NEG_SLOPE * e;
                a = __expf(e - m);
            }
            float4 v = ((const float4*)(x + (size_t)o * D))[lq];
            if (RELU_SRC) {
                v.x = fmaxf(v.x, 0.f); v.y = fmaxf(v.y, 0.f);
                v.z = fmaxf(v.z, 0.f); v.w = fmaxf(v.w, 0.f);
            }
            acc.x += a * v.x; acc.y += a * v.y;
            acc.z += a * v.z; acc.w += a * v.w;
        }
    }
    red4[t] = acc;
    __syncthreads();
    if (t < 32) {
        float4 s = red4[t];
        for (int g = 1; g < 8; ++g) {
            float4 v = red4[g * 32 + t];
            s.x += v.x; s.y += v.y; s.z += v.z; s.w += v.w;
        }
        s.x *= inv; s.y *= inv; s.z *= inv; s.w *= inv;
        ((float4*)(tout + (size_t)r * D))[t] = s;
    }
}

// ---------------------------------------------------------------------------
// layer-1 epilogue: r1 = relu(t1 @ Ws1 + b1); only alpha_d2 = r1·wdv2 survives
__global__ void gemm_l1(const float* __restrict__ t1, const float* __restrict__ Ws1,
                        const float* __restrict__ b1, const float* __restrict__ wdv2,
                        float* __restrict__ ad2r) {
    __shared__ float tl[D];
    __shared__ float red[D];
    int r = blockIdx.x, d = threadIdx.x;
    tl[d] = t1[(size_t)r * D + d];
    __syncthreads();
    float acc = 0.f;
    for (int k = 0; k < D; ++k) acc += tl[k] * Ws1[k * D + d];
    float v = fmaxf(acc + b1[d], 0.f);
    red[d] = v * wdv2[d];
    __syncthreads();
    for (int off = 64; off; off >>= 1) {
        if (d < off) red[d] += red[d + off];
        __syncthreads();
    }
    if (d == 0) ad2r[r] = red[0];
}

// layer-2 epilogue: r2 = t2 @ Ws2 + b2, materialized to workspace
__global__ void gemm_l2(const float* __restrict__ t2, const float* __restrict__ Ws2,
                        const float* __restrict__ b2, float* __restrict__ r2) {
    __shared__ float tl[D];
    int r = blockIdx.x, d = threadIdx.x;
    tl[d] = t2[(size_t)r * D + d];
    __syncthreads();
    float acc = 0.f;
    for (int k = 0; k < D; ++k) acc += tl[k] * Ws2[k * D + d];
    r2[(size_t)r * D + d] = acc + b2[d];
}

// ---------------------------------------------------------------------------
// edge-parallel scoring: one 32-lane half-wave per edge, float4 loads
__global__ void score_edges(const float* __restrict__ x, const float* __restrict__ r2,
                            const int* __restrict__ oi, const int* __restrict__ ri,
                            float* __restrict__ out) {
    int gid = blockIdx.x * blockDim.x + threadIdx.x;
    int e  = gid >> 5;
    int lq = gid & 31;
    if (e >= NE) return;
    int o = oi[e], r = ri[e];
    float4 xv = ((const float4*)(x  + (size_t)o * D))[lq];
    float4 rv = ((const float4*)(r2 + (size_t)r * D))[lq];
    float p = fmaxf(xv.x, 0.f) * rv.x + fmaxf(xv.y, 0.f) * rv.y +
              fmaxf(xv.z, 0.f) * rv.z + fmaxf(xv.w, 0.f) * rv.w;
    p += __shfl_xor(p, 16);
    p += __shfl_xor(p, 8);
    p += __shfl_xor(p, 4);
    p += __shfl_xor(p, 2);
    p += __shfl_xor(p, 1);
    if (lq == 0) out[e] = 1.f / (1.f + __expf(-p));
}

// ---------------------------------------------------------------------------
extern "C" void kernel_launch(void* const* d_in, const int* in_sizes, int n_in,
                              void* d_out, int out_size, void* d_ws, size_t ws_size,
                              hipStream_t stream) {
    const float* x_order = (const float*)d_in[0];
    const float* x_rider = (const float*)d_in[1];
    const int*   oi      = (const int*)d_in[2];
    const int*   ri      = (const int*)d_in[3];
    const float* Ws1 = (const float*)d_in[4];
    const float* Wd1 = (const float*)d_in[5];
    const float* as1 = (const float*)d_in[6];
    const float* ad1 = (const float*)d_in[7];
    const float* b1  = (const float*)d_in[8];
    const float* Ws2 = (const float*)d_in[9];
    const float* Wd2 = (const float*)d_in[10];
    const float* as2 = (const float*)d_in[11];
    const float* ad2 = (const float*)d_in[12];
    const float* b2  = (const float*)d_in[13];
    float* out = (float*)d_out;

    // workspace carve-up (all offsets 16B-aligned)
    char* w = (char*)d_ws;
    float* wsv1 = (float*)w; w += 512;
    float* wdv1 = (float*)w; w += 512;
    float* wsv2 = (float*)w; w += 512;
    float* wdv2 = (float*)w; w += 512;
    float* as1o = (float*)w; w += (size_t)NO * 4;      // 200000
    float* as2o = (float*)w; w += (size_t)NO * 4;
    float* ad1r = (float*)w; w += (size_t)NR * 4;      // 8000
    float* ad2r = (float*)w; w += (size_t)NR * 4;
    int* total  = (int*)w;   w += (size_t)NR * 4;
    int* starts = (int*)w;   w += (size_t)NR * 4;
    int* blockHist = (int*)w; w += (size_t)NR * NB * 4;  // 2 MB
    int* sOrd   = (int*)w;   w += (size_t)NE * 4;        // 2.4 MB
    float* t1   = (float*)w; w += (size_t)NR * D * 4;    // 1 MB
    float* t2   = (float*)w; w += (size_t)NR * D * 4;
    float* r2   = (float*)w; w += (size_t)NR * D * 4;

    precompute_wv<<<1, 128, 0, stream>>>(Ws1, as1, Wd1, ad1, Ws2, as2, Wd2, ad2,
                                         wsv1, wdv1, wsv2, wdv2);
    order_alphas<<<NO / 4, 256, 0, stream>>>(x_order, wsv1, wsv2, as1o, as2o);
    rider_alpha<<<NR / 4, 256, 0, stream>>>(x_rider, wdv1, ad1r);

    blockhist_kernel<<<NB, 256, 0, stream>>>(ri, blockHist);
    rowscan_kernel<<<(NR + 255) / 256, 256, 0, stream>>>(blockHist, total);
    scan_kernel<<<1, 256, 0, stream>>>(total, starts);
    scatter_kernel<<<NB, 256, 0, stream>>>(oi, ri, starts, blockHist, sOrd);

    rider_agg<false><<<NR, 256, 0, stream>>>(x_order, as1o, ad1r, starts, total, sOrd, t1);
    gemm_l1<<<NR, 128, 0, stream>>>(t1, Ws1, b1, wdv2, ad2r);
    rider_agg<true><<<NR, 256, 0, stream>>>(x_order, as2o, ad2r, starts, total, sOrd, t2);
    gemm_l2<<<NR, 128, 0, stream>>>(t2, Ws2, b2, r2);
    score_edges<<<NE / 8, 256, 0, stream>>>(x_order, r2, oi, ri, out);
}

// Round 5
// 242.106 us; speedup vs baseline: 2.8398x; 1.3103x over previous
//
#include <hip/hip_runtime.h>
#include <hip/hip_fp16.h>
#include <math.h>

#define NO 50000
#define NR 2000
#define NE 600000
#define D  128
#define NEG_SLOPE 0.2f
#define CAP 512   // max edges per rider cached in LDS (avg 300, max ~390)
#define NB 256    // sort chunk blocks
#define CH ((NE + NB - 1) / NB)   // 2344 edges per chunk

// ---------------------------------------------------------------------------
// wsv = W @ a  (four 128-vectors), one block of 128 threads
__global__ void precompute_wv(const float* __restrict__ Ws1, const float* __restrict__ as1,
                              const float* __restrict__ Wd1, const float* __restrict__ ad1,
                              const float* __restrict__ Ws2, const float* __restrict__ as2,
                              const float* __restrict__ Wd2, const float* __restrict__ ad2,
                              float* __restrict__ wsv1, float* __restrict__ wdv1,
                              float* __restrict__ wsv2, float* __restrict__ wdv2) {
    int k = threadIdx.x;
    float s1 = 0.f, d1 = 0.f, s2 = 0.f, d2 = 0.f;
    for (int j = 0; j < D; ++j) {
        s1 += Ws1[k * D + j] * as1[j];
        d1 += Wd1[k * D + j] * ad1[j];
        s2 += Ws2[k * D + j] * as2[j];
        d2 += Wd2[k * D + j] * ad2[j];
    }
    wsv1[k] = s1; wdv1[k] = d1; wsv2[k] = s2; wdv2[k] = d2;
}

// ---------------------------------------------------------------------------
// per-order: alphas (as1o = x·wsv1, as2o = relu(x)·wsv2) + fp16 conversion.
// One 64-lane wave per row; lane owns d = 2*lane, 2*lane+1 (float2).
__global__ void order_prep(const float* __restrict__ x,
                           const float* __restrict__ wsv1, const float* __restrict__ wsv2,
                           float* __restrict__ as1o, float* __restrict__ as2o,
                           __half* __restrict__ x16, __half* __restrict__ xr16) {
    int wave = (blockIdx.x * blockDim.x + threadIdx.x) >> 6;
    int lane = threadIdx.x & 63;
    if (wave >= NO) return;
    float2 xv = ((const float2*)(x + (size_t)wave * D))[lane];
    float2 w1 = ((const float2*)wsv1)[lane];
    float2 w2 = ((const float2*)wsv2)[lane];
    float rx0 = fmaxf(xv.x, 0.f), rx1 = fmaxf(xv.y, 0.f);
    ((__half2*)(x16  + (size_t)wave * D))[lane] = __floats2half2_rn(xv.x, xv.y);
    ((__half2*)(xr16 + (size_t)wave * D))[lane] = __floats2half2_rn(rx0, rx1);
    float a1 = xv.x * w1.x + xv.y * w1.y;
    float a2 = rx0 * w2.x + rx1 * w2.y;
    for (int off = 32; off; off >>= 1) {
        a1 += __shfl_down(a1, off);
        a2 += __shfl_down(a2, off);
    }
    if (lane == 0) { as1o[wave] = a1; as2o[wave] = a2; }
}

// per-rider alpha_d1 = x_rider · wdv1.  One wave per rider.
__global__ void rider_alpha(const float* __restrict__ xr, const float* __restrict__ wdv1,
                            float* __restrict__ ad1r) {
    int wave = (blockIdx.x * blockDim.x + threadIdx.x) >> 6;
    int lane = threadIdx.x & 63;
    if (wave >= NR) return;
    const float* row = xr + (size_t)wave * D;
    float a = row[lane] * wdv1[lane] + row[lane + 64] * wdv1[lane + 64];
    for (int off = 32; off; off >>= 1) a += __shfl_down(a, off);
    if (lane == 0) ad1r[wave] = a;
}

// ---------------------------------------------------------------------------
// contention-free counting sort of edges by rider (block-histogram method)
// blockHist layout: [b * NR + r]  (coalesced writes in A, coalesced scan in B1)

__global__ void blockhist_kernel(const int* __restrict__ ri, int* __restrict__ blockHist) {
    __shared__ int h[NR];
    int b = blockIdx.x, t = threadIdx.x;
    for (int i = t; i < NR; i += 256) h[i] = 0;
    __syncthreads();
    int lo = b * CH;
    int hi = lo + CH; if (hi > NE) hi = NE;
    for (int i = lo + t; i < hi; i += 256) atomicAdd(&h[ri[i]], 1);
    __syncthreads();
    for (int i = t; i < NR; i += 256) blockHist[(size_t)b * NR + i] = h[i];
}

__global__ void rowscan_kernel(int* __restrict__ blockHist, int* __restrict__ total) {
    int r = blockIdx.x * blockDim.x + threadIdx.x;
    if (r >= NR) return;
    int run = 0;
    for (int b = 0; b < NB; ++b) {
        int idx = b * NR + r;
        int v = blockHist[idx];
        blockHist[idx] = run;
        run += v;
    }
    total[r] = run;
}

__global__ void scan_kernel(const int* __restrict__ total, int* __restrict__ starts) {
    __shared__ int sums[256];
    int t = threadIdx.x;
    int v[8];
    int s = 0;
    for (int j = 0; j < 8; ++j) {
        int idx = t * 8 + j;
        int c = (idx < NR) ? total[idx] : 0;
        v[j] = s;
        s += c;
    }
    sums[t] = s;
    __syncthreads();
    for (int off = 1; off < 256; off <<= 1) {
        int add = (t >= off) ? sums[t - off] : 0;
        __syncthreads();
        sums[t] += add;
        __syncthreads();
    }
    int base = sums[t] - s;  // exclusive
    for (int j = 0; j < 8; ++j) {
        int idx = t * 8 + j;
        if (idx < NR) starts[idx] = base + v[j];
    }
}

__global__ void scatter_kernel(const int* __restrict__ oi, const int* __restrict__ ri,
                               const int* __restrict__ starts,
                               const int* __restrict__ blockHist,
                               int* __restrict__ sOrd) {
    __shared__ int h[NR];
    int b = blockIdx.x, t = threadIdx.x;
    for (int i = t; i < NR; i += 256) h[i] = 0;
    __syncthreads();
    int lo = b * CH;
    int hi = lo + CH; if (hi > NE) hi = NE;
    for (int i = lo + t; i < hi; i += 256) {
        int r = ri[i];
        int rank = atomicAdd(&h[r], 1);
        int pos = starts[r] + blockHist[(size_t)b * NR + r] + rank;
        sOrd[pos] = oi[i];
    }
}

// ---------------------------------------------------------------------------
// per-rider: segment softmax + fp16 gather-sum + fused 128x128 GEMM epilogue.
// L==1: t1 -> ad2r = relu(t1@Ws1+b1)·wdv2.   L==2: t2 -> r216 = fp16(t2@Ws2+b2).
// Pass 3: 16 groups x 16 lanes; lane lh owns d = lh*8..lh*8+7 (uint4 = 8 halfs).
template <int L>
__global__ void rider_agg(const __half* __restrict__ xg, const float* __restrict__ as_o,
                          const float* __restrict__ ad_r,
                          const int* __restrict__ starts, const int* __restrict__ cnt,
                          const int* __restrict__ sOrd,
                          const float* __restrict__ W, const float* __restrict__ bias,
                          const float* __restrict__ wdv2,
                          float* __restrict__ ad2r, __half* __restrict__ r216) {
    __shared__ float eL[CAP];
    __shared__ int   sO[CAP];
    __shared__ float red[256];
    __shared__ float red8[256][9];   // +1 pad breaks 8-stride bank conflicts
    __shared__ float tl[D];
    int r = blockIdx.x;
    int t = threadIdx.x;
    int base = starts[r], n = cnt[r];
    float ad = ad_r[r];

    // pass 1: leaky-relu'd logits + max
    float lmax = -1e30f;
    for (int i = t; i < n; i += 256) {
        int o = sOrd[base + i];
        float e = as_o[o] + ad;
        e = (e > 0.f) ? e : NEG_SLOPE * e;
        if (i < CAP) { eL[i] = e; sO[i] = o; }
        lmax = fmaxf(lmax, e);
    }
    red[t] = lmax;
    __syncthreads();
    for (int off = 128; off; off >>= 1) {
        if (t < off) red[t] = fmaxf(red[t], red[t + off]);
        __syncthreads();
    }
    float m = red[0];
    __syncthreads();

    // pass 2: exp + sum (1/s folded at the end)
    float ls = 0.f;
    for (int i = t; i < n; i += 256) {
        float e;
        if (i < CAP) e = eL[i];
        else {
            int o = sOrd[base + i];
            e = as_o[o] + ad;
            e = (e > 0.f) ? e : NEG_SLOPE * e;
        }
        float ex = __expf(e - m);
        if (i < CAP) eL[i] = ex;
        ls += ex;
    }
    red[t] = ls;
    __syncthreads();
    for (int off = 128; off; off >>= 1) {
        if (t < off) red[t] += red[t + off];
        __syncthreads();
    }
    float inv = 1.f / (red[0] + 1e-16f);
    __syncthreads();

    // pass 3: fp16 gather, 16 edge-groups x 16 lanes, 8 d's per lane
    int grp = t >> 4;
    int lh  = t & 15;
    float acc[8];
#pragma unroll
    for (int k = 0; k < 8; ++k) acc[k] = 0.f;
    for (int i = grp; i < n; i += 16) {
        float a; int o;
        if (i < CAP) { a = eL[i]; o = sO[i]; }
        else {
            o = sOrd[base + i];
            float e = as_o[o] + ad;
            e = (e > 0.f) ? e : NEG_SLOPE * e;
            a = __expf(e - m);
        }
        uint4 hv = ((const uint4*)(xg + (size_t)o * D))[lh];
        float2 f0 = __half22float2(*(const __half2*)&hv.x);
        float2 f1 = __half22float2(*(const __half2*)&hv.y);
        float2 f2 = __half22float2(*(const __half2*)&hv.z);
        float2 f3 = __half22float2(*(const __half2*)&hv.w);
        acc[0] += a * f0.x; acc[1] += a * f0.y;
        acc[2] += a * f1.x; acc[3] += a * f1.y;
        acc[4] += a * f2.x; acc[5] += a * f2.y;
        acc[6] += a * f3.x; acc[7] += a * f3.y;
    }
#pragma unroll
    for (int k = 0; k < 8; ++k) red8[t][k] = acc[k];
    __syncthreads();
    if (t < D) {
        int lh2 = t >> 3, k = t & 7;
        float s = 0.f;
        for (int g = 0; g < 16; ++g) s += red8[g * 16 + lh2][k];
        tl[t] = s * inv;
    }
    __syncthreads();

    // fused epilogue GEMM: 256 threads, d = t&127, k-half = t>>7
    int d = t & 127, h = t >> 7;
    float acc2 = 0.f;
    for (int k = h * 64; k < h * 64 + 64; ++k) acc2 += tl[k] * W[k * D + d];
    red[t] = acc2;
    __syncthreads();
    if (L == 1) {
        if (t < 128) red[t] = fmaxf(red[t] + red[t + 128] + bias[t], 0.f) * wdv2[t];
        __syncthreads();
        for (int off = 64; off; off >>= 1) {
            if (t < off) red[t] += red[t + off];
            __syncthreads();
        }
        if (t == 0) ad2r[r] = red[0];
    } else {
        if (t < 128) r216[(size_t)r * D + t] = __float2half(red[t] + red[t + 128] + bias[t]);
    }
}

// ---------------------------------------------------------------------------
// edge-parallel scoring: 16 lanes per edge, fp16 both sides
__global__ void score_edges(const __half* __restrict__ xr16, const __half* __restrict__ r216,
                            const int* __restrict__ oi, const int* __restrict__ ri,
                            float* __restrict__ out) {
    int gid = blockIdx.x * blockDim.x + threadIdx.x;
    int e  = gid >> 4;
    int lh = gid & 15;
    if (e >= NE) return;
    int o = oi[e], r = ri[e];
    uint4 hx = ((const uint4*)(xr16 + (size_t)o * D))[lh];
    uint4 hr = ((const uint4*)(r216 + (size_t)r * D))[lh];
    float2 a0 = __half22float2(*(const __half2*)&hx.x);
    float2 a1 = __half22float2(*(const __half2*)&hx.y);
    float2 a2 = __half22float2(*(const __half2*)&hx.z);
    float2 a3 = __half22float2(*(const __half2*)&hx.w);
    float2 b0 = __half22float2(*(const __half2*)&hr.x);
    float2 b1 = __half22float2(*(const __half2*)&hr.y);
    float2 b2 = __half22float2(*(const __half2*)&hr.z);
    float2 b3 = __half22float2(*(const __half2*)&hr.w);
    float p = a0.x * b0.x + a0.y * b0.y + a1.x * b1.x + a1.y * b1.y +
              a2.x * b2.x + a2.y * b2.y + a3.x * b3.x + a3.y * b3.y;
    p += __shfl_xor(p, 8);
    p += __shfl_xor(p, 4);
    p += __shfl_xor(p, 2);
    p += __shfl_xor(p, 1);
    if (lh == 0) out[e] = 1.f / (1.f + __expf(-p));
}

// ---------------------------------------------------------------------------
extern "C" void kernel_launch(void* const* d_in, const int* in_sizes, int n_in,
                              void* d_out, int out_size, void* d_ws, size_t ws_size,
                              hipStream_t stream) {
    const float* x_order = (const float*)d_in[0];
    const float* x_rider = (const float*)d_in[1];
    const int*   oi      = (const int*)d_in[2];
    const int*   ri      = (const int*)d_in[3];
    const float* Ws1 = (const float*)d_in[4];
    const float* Wd1 = (const float*)d_in[5];
    const float* as1 = (const float*)d_in[6];
    const float* ad1 = (const float*)d_in[7];
    const float* b1  = (const float*)d_in[8];
    const float* Ws2 = (const float*)d_in[9];
    const float* Wd2 = (const float*)d_in[10];
    const float* as2 = (const float*)d_in[11];
    const float* ad2 = (const float*)d_in[12];
    const float* b2  = (const float*)d_in[13];
    float* out = (float*)d_out;

    // workspace carve-up (16B-aligned chunks)
    char* w = (char*)d_ws;
    float* wsv1 = (float*)w; w += 512;
    float* wdv1 = (float*)w; w += 512;
    float* wsv2 = (float*)w; w += 512;
    float* wdv2 = (float*)w; w += 512;
    float* as1o = (float*)w; w += (size_t)NO * 4;        // 200 KB
    float* as2o = (float*)w; w += (size_t)NO * 4;
    float* ad1r = (float*)w; w += (size_t)NR * 4;        // 8 KB
    float* ad2r = (float*)w; w += (size_t)NR * 4;
    int* total  = (int*)w;   w += (size_t)NR * 4;
    int* starts = (int*)w;   w += (size_t)NR * 4;
    int* blockHist = (int*)w; w += (size_t)NB * NR * 4;  // 2 MB
    int* sOrd   = (int*)w;   w += (size_t)NE * 4;        // 2.4 MB
    __half* x16  = (__half*)w; w += (size_t)NO * D * 2;  // 12.8 MB
    __half* xr16 = (__half*)w; w += (size_t)NO * D * 2;  // 12.8 MB
    __half* r216 = (__half*)w; w += (size_t)NR * D * 2;  // 512 KB

    precompute_wv<<<1, 128, 0, stream>>>(Ws1, as1, Wd1, ad1, Ws2, as2, Wd2, ad2,
                                         wsv1, wdv1, wsv2, wdv2);
    order_prep<<<NO / 4, 256, 0, stream>>>(x_order, wsv1, wsv2, as1o, as2o, x16, xr16);
    rider_alpha<<<NR / 4, 256, 0, stream>>>(x_rider, wdv1, ad1r);

    blockhist_kernel<<<NB, 256, 0, stream>>>(ri, blockHist);
    rowscan_kernel<<<(NR + 255) / 256, 256, 0, stream>>>(blockHist, total);
    scan_kernel<<<1, 256, 0, stream>>>(total, starts);
    scatter_kernel<<<NB, 256, 0, stream>>>(oi, ri, starts, blockHist, sOrd);

    rider_agg<1><<<NR, 256, 0, stream>>>(x16, as1o, ad1r, starts, total, sOrd,
                                         Ws1, b1, wdv2, ad2r, ((__half*)0));
    rider_agg<2><<<NR, 256, 0, stream>>>(xr16, as2o, ad2r, starts, total, sOrd,
                                         Ws2, b2, wdv2, (float*)0, r216);
    score_edges<<<(NE * 16 + 255) / 256, 256, 0, stream>>>(xr16, r216, oi, ri, out);
}